// Round 1
// baseline (840.486 us; speedup 1.0000x reference)
//
#include <hip/hip_runtime.h>
#include <hip/hip_bf16.h>

#define D 8192
#define M_TIME 16
#define RMS_EPS 1e-6f
#define DEN_EPS 1e-9f
#define KWTA_K 1024  // D/8

// ---------------- Kernel 1: x = rmsnorm(x_in + pred) * norm_w ----------------
__global__ __launch_bounds__(1024) void k_rmsnorm(const float* __restrict__ x_in,
                                                  const float* __restrict__ pred,
                                                  const float* __restrict__ norm_w,
                                                  float* __restrict__ x) {
    __shared__ float red[16];
    __shared__ float s_rs;
    int tid = threadIdx.x;  // 1024 threads, 8 elems each
    float t[8];
    float acc = 0.f;
#pragma unroll
    for (int j = 0; j < 8; ++j) {
        int i = tid + j * 1024;
        t[j] = x_in[i] + pred[i];
        acc += t[j] * t[j];
    }
#pragma unroll
    for (int off = 32; off; off >>= 1) acc += __shfl_down(acc, off);
    int lane = tid & 63, wv = tid >> 6;
    if (lane == 0) red[wv] = acc;
    __syncthreads();
    if (tid == 0) {
        float s = 0.f;
        for (int i = 0; i < 16; ++i) s += red[i];
        s_rs = rsqrtf(s / (float)D + RMS_EPS);
    }
    __syncthreads();
    float rs = s_rs;
#pragma unroll
    for (int j = 0; j < 8; ++j) {
        int i = tid + j * 1024;
        x[i] = t[j] * rs * norm_w[i];
    }
}

// ---------------- Kernel 2: r = sigmoid(Wr@x), w = exp(Wk@x), v = Wv@x -------
// One wave per output row; 3*8192 rows total. float4 coalesced row reads.
__global__ __launch_bounds__(256) void k_matvec3(const float* __restrict__ Wr,
                                                 const float* __restrict__ Wk,
                                                 const float* __restrict__ Wv,
                                                 const float* __restrict__ x,
                                                 float* __restrict__ r,
                                                 float* __restrict__ w,
                                                 float* __restrict__ v) {
    int wave = (blockIdx.x * 256 + threadIdx.x) >> 6;  // 0 .. 3*8192-1
    int lane = threadIdx.x & 63;
    int mat = wave >> 13;        // wave / 8192
    int row = wave & (D - 1);
    const float* W = (mat == 0) ? Wr : (mat == 1) ? Wk : Wv;
    const float4* Wrow = (const float4*)(W + (size_t)row * D);
    const float4* xv = (const float4*)x;
    float acc = 0.f;
#pragma unroll 8
    for (int it = 0; it < D / 256; ++it) {   // 32 iters
        float4 a = Wrow[it * 64 + lane];
        float4 b = xv[it * 64 + lane];
        acc += a.x * b.x + a.y * b.y + a.z * b.z + a.w * b.w;
    }
#pragma unroll
    for (int off = 32; off; off >>= 1) acc += __shfl_down(acc, off);
    if (lane == 0) {
        if (mat == 0)      r[row] = 1.f / (1.f + expf(-acc));
        else if (mat == 1) w[row] = expf(acc);
        else               v[row] = acc;
    }
}

// ---------------- Kernel 3: rope + state mix -> y ----------------------------
__global__ __launch_bounds__(256) void k_mix(const float* __restrict__ state_num,
                                             const float* __restrict__ state_den,
                                             const float* __restrict__ decay,
                                             const float* __restrict__ W_time,
                                             const float* __restrict__ step_pos,
                                             const int* __restrict__ dt,
                                             const float* __restrict__ r,
                                             const float* __restrict__ w,
                                             const float* __restrict__ v,
                                             float* __restrict__ y) {
    int i = blockIdx.x * 256 + threadIdx.x;
    if (i >= D) return;
    float z = decay[i];
    float sg = 1.f / (1.f + expf(-z));
    float lam = sg * sg;
    float mul = powf(lam, (float)dt[0]);
    float sn = state_num[i] * mul;
    float sd = state_den[i] * mul;
    float vi = v[i];
    if (i < 2 * M_TIME) {
        int p = i >> 1;
        float th = step_pos[0] * W_time[p];
        float c = cosf(th), s = sinf(th);
        float v0 = v[2 * p], v1 = v[2 * p + 1];
        vi = (i & 1) ? (v0 * s + v1 * c) : (v0 * c - v1 * s);
    }
    float wi = w[i];
    float sn2 = sn * lam + wi * vi;
    float sd2 = sd * lam + wi;
    y[i] = r[i] * (sn2 / (sd2 + DEN_EPS));
}

// ---------------- Kernel 4: h = x + Wo@y -------------------------------------
__global__ __launch_bounds__(256) void k_matvec_o(const float* __restrict__ Wo,
                                                  const float* __restrict__ y,
                                                  const float* __restrict__ x,
                                                  float* __restrict__ h) {
    int row = (blockIdx.x * 256 + threadIdx.x) >> 6;
    int lane = threadIdx.x & 63;
    const float4* Wrow = (const float4*)(Wo + (size_t)row * D);
    const float4* yv = (const float4*)y;
    float acc = 0.f;
#pragma unroll 8
    for (int it = 0; it < D / 256; ++it) {
        float4 a = Wrow[it * 64 + lane];
        float4 b = yv[it * 64 + lane];
        acc += a.x * b.x + a.y * b.y + a.z * b.z + a.w * b.w;
    }
#pragma unroll
    for (int off = 32; off; off >>= 1) acc += __shfl_down(acc, off);
    if (lane == 0) h[row] = x[row] + acc;
}

// ---------------- Kernel 5: exact kWTA via radix-select ----------------------
// Finds the KWTA_K-th largest |h| exactly (bit-level radix select, MSB-first),
// then out[i] = |h[i]| >= thr ? h[i] : 0  — matches top_k + where semantics.
__global__ __launch_bounds__(1024) void k_kwta(const float* __restrict__ h,
                                               float* __restrict__ out) {
    __shared__ unsigned hist[256];
    __shared__ unsigned sh_prefix;
    __shared__ unsigned sh_k;
    int tid = threadIdx.x;  // 1024 threads, 8 elems each
    float hv[8];
    unsigned ab[8];
#pragma unroll
    for (int j = 0; j < 8; ++j) {
        hv[j] = h[tid + j * 1024];
        ab[j] = __float_as_uint(hv[j]) & 0x7fffffffu;  // |h| bits (monotonic)
    }
    if (tid == 0) { sh_prefix = 0u; sh_k = KWTA_K; }
    __syncthreads();
    for (int shift = 24; shift >= 0; shift -= 8) {
        if (tid < 256) hist[tid] = 0u;
        __syncthreads();
        unsigned pref = sh_prefix;
#pragma unroll
        for (int j = 0; j < 8; ++j) {
            unsigned b = ab[j];
            bool match = (shift == 24) || ((b >> (shift + 8)) == pref);
            if (match) atomicAdd(&hist[(b >> shift) & 0xffu], 1u);
        }
        __syncthreads();
        if (tid == 0) {
            unsigned cum = 0;
            int bin = 255;
            for (; bin > 0; --bin) {
                unsigned c = hist[bin];
                if (cum + c >= sh_k) break;
                cum += c;
            }
            sh_prefix = (pref << 8) | (unsigned)bin;
            sh_k = sh_k - cum;
        }
        __syncthreads();
    }
    unsigned thr = sh_prefix;
#pragma unroll
    for (int j = 0; j < 8; ++j) {
        out[tid + j * 1024] = (ab[j] >= thr) ? hv[j] : 0.0f;
    }
}

// ---------------- launch ------------------------------------------------------
extern "C" void kernel_launch(void* const* d_in, const int* in_sizes, int n_in,
                              void* d_out, int out_size, void* d_ws, size_t ws_size,
                              hipStream_t stream) {
    const float* x_in      = (const float*)d_in[0];
    const float* state_num = (const float*)d_in[1];
    const float* state_den = (const float*)d_in[2];
    const float* pred      = (const float*)d_in[3];
    const float* norm_w    = (const float*)d_in[4];
    const float* Wr        = (const float*)d_in[5];
    const float* Wk        = (const float*)d_in[6];
    const float* Wv        = (const float*)d_in[7];
    const float* Wo        = (const float*)d_in[8];
    const float* decay     = (const float*)d_in[9];
    const float* W_time    = (const float*)d_in[10];
    const float* step_pos  = (const float*)d_in[11];
    const int*   dt        = (const int*)d_in[12];

    float* ws = (float*)d_ws;
    float* x = ws;              // D
    float* r = ws + D;          // D
    float* w = ws + 2 * D;      // D
    float* v = ws + 3 * D;      // D
    float* y = ws + 4 * D;      // D
    float* h = ws + 5 * D;      // D

    float* out = (float*)d_out;

    k_rmsnorm<<<1, 1024, 0, stream>>>(x_in, pred, norm_w, x);
    k_matvec3<<<(3 * D) / 4, 256, 0, stream>>>(Wr, Wk, Wv, x, r, w, v);
    k_mix<<<D / 256, 256, 0, stream>>>(state_num, state_den, decay, W_time,
                                       step_pos, dt, r, w, v, y);
    k_matvec_o<<<D / 4, 256, 0, stream>>>(Wo, y, x, h);
    k_kwta<<<1, 1024, 0, stream>>>(h, out);
}